// Round 15
// baseline (65.521 us; speedup 1.0000x reference)
//
#include <hip/hip_runtime.h>
#include <math.h>

#define BB 4
#define SS 4096
#define DD 768
#define HH 64
#define MM (BB * SS)

typedef __attribute__((ext_vector_type(8))) short bf16x8;
typedef __attribute__((ext_vector_type(4))) float f32x4;

__device__ inline unsigned short f2bf(float f) {
    union { float f; unsigned u; } x; x.f = f;
    unsigned r = x.u + 0x7fffu + ((x.u >> 16) & 1u);
    return (unsigned short)(r >> 16);
}

// packed f32x2 -> bf16x2 (lo=a, hi=b); no builtin on gfx950, use inline asm (guide T12)
__device__ inline unsigned cvtpk(float a, float b) {
    unsigned r;
    asm("v_cvt_pk_bf16_f32 %0, %1, %2" : "=v"(r) : "v"(a), "v"(b));
    return r;
}

// XOR-swizzle for [rows][64 bf16] (128B-row) LDS tiles: 16B slot ^= row&7.
// Apply on BOTH write and read (same involution both sides).
__device__ inline unsigned short* swzp(unsigned short* base, int byteoff) {
    byteoff ^= ((byteoff >> 7) & 7) << 4;
    return (unsigned short*)((char*)base + byteoff);
}

// ---------------- One-time weight transpose: Wq|Wk|Wv [768,64] fp32 -> Wt [192][768] bf16 ----------------
__global__ __launch_bounds__(256) void wt_kernel(
    const float* __restrict__ Wq, const float* __restrict__ Wk, const float* __restrict__ Wv,
    unsigned short* __restrict__ Wt)
{
    const int kt = blockIdx.x;
    const int sel = blockIdx.y;
    const int k0 = kt * 64;
    const float* W = (sel == 0) ? Wq : (sel == 1) ? Wk : Wv;
    __shared__ float Ws[64][68];
    const int t = threadIdx.x;
    #pragma unroll
    for (int j = 0; j < 4; ++j) {
        const int fl = t + j * 256;
        const int row = fl >> 4, c4 = (fl & 15) * 4;
        float4 v = *reinterpret_cast<const float4*>(&W[(size_t)(k0 + row) * HH + c4]);
        Ws[row][c4 + 0] = v.x; Ws[row][c4 + 1] = v.y;
        Ws[row][c4 + 2] = v.z; Ws[row][c4 + 3] = v.w;
    }
    __syncthreads();
    const int n = t >> 2;
    const int c8 = (t & 3) * 16;
    unsigned short tmp[16];
    #pragma unroll
    for (int j = 0; j < 16; ++j) tmp[j] = f2bf(Ws[c8 + j][n]);
    unsigned short* dst = &Wt[((size_t)sel * 64 + n) * DD + k0 + c8];
    *reinterpret_cast<bf16x8*>(dst)     = *reinterpret_cast<bf16x8*>(&tmp[0]);
    *reinterpret_cast<bf16x8*>(dst + 8) = *reinterpret_cast<bf16x8*>(&tmp[8]);
}

// ---------------- QKV projection via MFMA: M=32, N=192, BK=64, reg ping-pong, swizzled LDS ----------------
#define VTP 40
__global__ __launch_bounds__(512) void qkv_proj_kernel(
    const float* __restrict__ X, const unsigned short* __restrict__ Wt,
    const float* __restrict__ bq, const float* __restrict__ bk, const float* __restrict__ bv,
    unsigned short* __restrict__ Qb, unsigned short* __restrict__ Kb,
    unsigned short* __restrict__ Vt)
{
    __shared__ unsigned short Alds[32 * 64];
    __shared__ unsigned short Blds[192 * 64];

    const int tid = threadIdx.x;
    const int rowBase = blockIdx.x * 32;
    const int w = tid >> 6;
    const int ms = w & 1;
    const int nq = w >> 1;
    const int lane = tid & 63;
    const int lhi = lane >> 4, llo = lane & 15;

    f32x4 acc[3] = {{0,0,0,0},{0,0,0,0},{0,0,0,0}};

    const int arow = tid >> 4;
    const int ac   = (tid & 15) * 4;

    float4 xA, xB;
    bf16x8 bA[3], bB[3];

    auto loadP = [&](int kb, float4& x0, bf16x8 (&bb)[3]) {
        const int kBase = kb * 64;
        x0 = *reinterpret_cast<const float4*>(&X[(size_t)(rowBase + arow) * DD + kBase + ac]);
        #pragma unroll
        for (int i = 0; i < 3; ++i) {
            const int u = tid + i * 512;
            const int n = u >> 3, c8 = (u & 7) * 8;
            bb[i] = *reinterpret_cast<const bf16x8*>(&Wt[(size_t)n * DD + kBase + c8]);
        }
    };
    auto writeP = [&](const float4& x0, bf16x8 (&bb)[3]) {
        uint2 pk;
        pk.x = cvtpk(x0.x, x0.y);
        pk.y = cvtpk(x0.z, x0.w);
        *reinterpret_cast<uint2*>(swzp(Alds, (arow * 64 + ac) * 2)) = pk;
        #pragma unroll
        for (int i = 0; i < 3; ++i) {
            const int u = tid + i * 512;
            const int n = u >> 3, c8 = (u & 7) * 8;
            *reinterpret_cast<bf16x8*>(swzp(Blds, (n * 64 + c8) * 2)) = bb[i];
        }
    };

    loadP(0, xA, bA);

    for (int kb = 0; kb < DD / 64; ++kb) {
        __syncthreads();
        if ((kb & 1) == 0) {
            writeP(xA, bA);
            if (kb + 1 < DD / 64) loadP(kb + 1, xB, bB);
        } else {
            writeP(xB, bB);
            if (kb + 1 < DD / 64) loadP(kb + 1, xA, bA);
        }
        __syncthreads();

        #pragma unroll
        for (int kk = 0; kk < 2; ++kk) {
            const int aoff = kk * 32 + lhi * 8;
            bf16x8 af = *reinterpret_cast<const bf16x8*>(
                swzp(Alds, ((ms * 16 + llo) * 64 + aoff) * 2));
            #pragma unroll
            for (int nt = 0; nt < 3; ++nt) {
                bf16x8 bf = *reinterpret_cast<const bf16x8*>(
                    swzp(Blds, ((nq * 48 + nt * 16 + llo) * 64 + aoff) * 2));
                acc[nt] = __builtin_amdgcn_mfma_f32_16x16x32_bf16(af, bf, acc[nt], 0, 0, 0);
            }
        }
    }

    // ---- epilogue ----
    __syncthreads();
    unsigned short* VtLds = Blds;   // [64 nn][VTP] bf16

    #pragma unroll
    for (int nt = 0; nt < 3; ++nt) {
        const int n = nq * 48 + nt * 16 + llo;
        const int sel = n >> 6;
        const int nn = n & 63;
        const float bias = (sel == 0) ? bq[nn] : (sel == 1) ? bk[nn] : bv[nn];
        if (sel == 0) {
            #pragma unroll
            for (int r = 0; r < 4; ++r) {
                const int row = rowBase + ms * 16 + lhi * 4 + r;
                Qb[(size_t)row * HH + nn] = f2bf((acc[nt][r] + bias) * 0.125f);
            }
        } else if (sel == 1) {
            #pragma unroll
            for (int r = 0; r < 4; ++r) {
                const int row = rowBase + ms * 16 + lhi * 4 + r;
                Kb[(size_t)row * HH + nn] = f2bf(acc[nt][r] + bias);
            }
        } else {
            uint2 pk;
            pk.x = cvtpk(acc[nt][0] + bias, acc[nt][1] + bias);
            pk.y = cvtpk(acc[nt][2] + bias, acc[nt][3] + bias);
            *reinterpret_cast<uint2*>(&VtLds[nn * VTP + ms * 16 + lhi * 4]) = pk;
        }
    }
    __syncthreads();
    if (tid < 256) {
        const int nn = tid >> 2;
        const int s8 = (tid & 3) * 8;
        const int bb = rowBase >> 12;
        const int sbase = rowBase & (SS - 1);
        bf16x8 v = *reinterpret_cast<const bf16x8*>(&VtLds[nn * VTP + s8]);
        *reinterpret_cast<bf16x8*>(&Vt[((size_t)bb * HH + nn) * SS + sbase + s8]) = v;
    }
}

// ---------------- Split-K MFMA flash attention: 256 thr, 32 q-rows/wave ----------------
// 4 waves: g = w>>1 (tile parity), wq2 = w&1 (32-row q half). Each wave reads a
// K/V fragment ONCE and feeds two q-strips (2 Q B-operands) -> LDS reads halved.
union SMemA {
    struct {
        unsigned short K[2 * 4096];          // 2 tiles [64][64], swizzled  (16 KB)
        unsigned short V[2 * 4096];          // 2 tiles [64][64], swizzled  (16 KB)
        unsigned short Pl[4][32][72];        // per-wave P (32 q rows)      (18 KB)
    } st;
    struct { float O[64][68]; float ml[64][2]; } cb;   // 17920 B
};

__global__ __launch_bounds__(256, 3) void attn_partial_kernel(
    const unsigned short* __restrict__ Qg, const unsigned short* __restrict__ Kg,
    const unsigned short* __restrict__ Vtg, float* __restrict__ out,
    float* __restrict__ Po, float* __restrict__ Pml)
{
    __shared__ SMemA sm;

    // ---- LPT (longest-first) decode: idx -> (b, qb, c) ----
    const int idx = blockIdx.x;
    const int l = idx >> 2;
    const int b = idx & 3;
    int qb, c;
    if (l < 49)       { qb = 15 + l;        c = 0; }
    else if (l < 82)  { qb = 31 + (l - 49); c = 1; }
    else if (l < 99)  { qb = 47 + (l - 82); c = 2; }
    else if (l == 99) { qb = 63;            c = 3; }
    else {
        const int j = l - 100;
        const int s = 15 - (j >> 2);
        const int k = j & 3;
        qb = (s - 1) + 16 * k;
        c = k;
    }

    const int tid = threadIdx.x;
    const int q0 = qb * 64;
    const int w    = tid >> 6;       // 0..3
    const int g    = w >> 1;         // tile parity
    const int wq2  = w & 1;          // 32-row q half
    const int lane = tid & 63;
    const int lhi = lane >> 4, llo = lane & 15;
    const int qw0A = q0 + wq2 * 32;        // strip A base
    const int qw0B = qw0A + 16;            // strip B base
    const int qmeA = qw0A + llo;
    const int qmeB = qw0B + llo;

    const int ntiles = qb + 1;
    const int base0 = c * 16;
    const int endT = min(base0 + 16, ntiles);
    const int nsteps = (endT - base0 + 1) >> 1;
    const int nch = qb / 16 + 1;

    const unsigned short* Kbase = Kg  + (size_t)b * SS * HH;
    const unsigned short* Vbase = Vtg + (size_t)b * HH * SS;

    // Q fragments (B operands) for both strips
    bf16x8 qfA0, qfA1, qfB0, qfB1;
    {
        const unsigned short* qa = Qg + ((size_t)b * SS + qmeA) * HH + lhi * 8;
        qfA0 = *reinterpret_cast<const bf16x8*>(qa);
        qfA1 = *reinterpret_cast<const bf16x8*>(qa + 32);
        const unsigned short* qbp = Qg + ((size_t)b * SS + qmeB) * HH + lhi * 8;
        qfB0 = *reinterpret_cast<const bf16x8*>(qbp);
        qfB1 = *reinterpret_cast<const bf16x8*>(qbp + 32);
    }

    float mA = -INFINITY, lsumA = 0.f;
    float mB = -INFINITY, lsumB = 0.f;
    f32x4 accA[4] = {{0,0,0,0},{0,0,0,0},{0,0,0,0},{0,0,0,0}};
    f32x4 accB[4] = {{0,0,0,0},{0,0,0,0},{0,0,0,0},{0,0,0,0}};

    bf16x8 rA[8], rB[8];
    #pragma unroll
    for (int i = 0; i < 8; ++i) { rA[i] = bf16x8{0,0,0,0,0,0,0,0}; rB[i] = bf16x8{0,0,0,0,0,0,0,0}; }

    // staging: 256 threads x 8 bf16x8 = 2 K-tiles + 2 V-tiles (32 KB)
    auto load_step = [&](int base, bf16x8 (&rg)[8]) {
        #pragma unroll
        for (int i = 0; i < 8; ++i) {
            const int pt = (i >> 1) & 1;          // tile parity
            const int t = base + pt;
            const int u = tid + (i & 1) * 256;    // 0..511
            const int row = u >> 3, c8 = (u & 7) * 8;
            if (t < endT) {
                rg[i] = (i < 4)
                    ? *reinterpret_cast<const bf16x8*>(&Kbase[(size_t)(t * 64 + row) * HH + c8])
                    : *reinterpret_cast<const bf16x8*>(&Vbase[(size_t)row * SS + t * 64 + c8]);
            }
        }
    };
    auto write_step = [&](bf16x8 (&rg)[8]) {
        #pragma unroll
        for (int i = 0; i < 8; ++i) {
            const int pt = (i >> 1) & 1;
            const int u = tid + (i & 1) * 256;
            const int row = u >> 3, c8 = (u & 7) * 8;
            const int ro = pt * 8192 + (row * 64 + c8) * 2;
            if (i < 4) *reinterpret_cast<bf16x8*>(swzp(sm.st.K, ro)) = rg[i];
            else       *reinterpret_cast<bf16x8*>(swzp(sm.st.V, ro)) = rg[i];
        }
    };

    load_step(base0, rA);

    for (int stp = 0; stp < nsteps; ++stp) {
        const int base = base0 + stp * 2;
        __syncthreads();
        if ((stp & 1) == 0) {
            write_step(rA);
            if (stp + 1 < nsteps) load_step(base + 2, rB);
        } else {
            write_step(rB);
            if (stp + 1 < nsteps) load_step(base + 2, rA);
        }
        __syncthreads();

        const int lt = base + g;
        if (lt < endT) {
            const int k0 = lt * 64;
            const int tb = g * 8192;

            // ---- S^T = K Q^T for both strips (K frags read once) ----
            f32x4 sA[4] = {{0,0,0,0},{0,0,0,0},{0,0,0,0},{0,0,0,0}};
            f32x4 sB[4] = {{0,0,0,0},{0,0,0,0},{0,0,0,0},{0,0,0,0}};
            __builtin_amdgcn_s_setprio(1);
            #pragma unroll
            for (int kt = 0; kt < 4; ++kt) {
                const int rbo = tb + ((kt * 16 + llo) * 64) * 2;
                bf16x8 ka = *reinterpret_cast<const bf16x8*>(swzp(sm.st.K, rbo + lhi * 16));
                bf16x8 kb = *reinterpret_cast<const bf16x8*>(swzp(sm.st.K, rbo + 64 + lhi * 16));
                sA[kt] = __builtin_amdgcn_mfma_f32_16x16x32_bf16(ka, qfA0, sA[kt], 0, 0, 0);
                sA[kt] = __builtin_amdgcn_mfma_f32_16x16x32_bf16(kb, qfA1, sA[kt], 0, 0, 0);
                sB[kt] = __builtin_amdgcn_mfma_f32_16x16x32_bf16(ka, qfB0, sB[kt], 0, 0, 0);
                sB[kt] = __builtin_amdgcn_mfma_f32_16x16x32_bf16(kb, qfB1, sB[kt], 0, 0, 0);
            }
            __builtin_amdgcn_s_setprio(0);

            // ---- causal mask (diagonal tiles only, per strip) ----
            if (k0 + 63 > qw0A) {
                #pragma unroll
                for (int kt = 0; kt < 4; ++kt) {
                    #pragma unroll
                    for (int r = 0; r < 4; ++r) {
                        const int key = k0 + kt * 16 + lhi * 4 + r;
                        if (key > qmeA) sA[kt][r] = -INFINITY;
                        if (key > qmeB) sB[kt][r] = -INFINITY;
                    }
                }
            }

            // ---- per-lane online softmax, two independent states, defer-max ----
            float mxA = sA[0][0], mxB = sB[0][0];
            #pragma unroll
            for (int kt = 0; kt < 4; ++kt)
                #pragma unroll
                for (int r = 0; r < 4; ++r) { mxA = fmaxf(mxA, sA[kt][r]); mxB = fmaxf(mxB, sB[kt][r]); }
            mxA = fmaxf(mxA, __shfl_xor(mxA, 16));
            mxA = fmaxf(mxA, __shfl_xor(mxA, 32));
            mxB = fmaxf(mxB, __shfl_xor(mxB, 16));
            mxB = fmaxf(mxB, __shfl_xor(mxB, 32));
            if (!__all(mxA - mA <= 8.0f)) {
                const float mn = fmaxf(mA, mxA);
                const float corr = __expf(mA - mn);
                lsumA *= corr;
                #pragma unroll
                for (int dt = 0; dt < 4; ++dt)
                    #pragma unroll
                    for (int r = 0; r < 4; ++r) accA[dt][r] *= corr;
                mA = mn;
            }
            if (!__all(mxB - mB <= 8.0f)) {
                const float mn = fmaxf(mB, mxB);
                const float corr = __expf(mB - mn);
                lsumB *= corr;
                #pragma unroll
                for (int dt = 0; dt < 4; ++dt)
                    #pragma unroll
                    for (int r = 0; r < 4; ++r) accB[dt][r] *= corr;
                mB = mn;
            }
            float psA = 0.f, psB = 0.f;
            #pragma unroll
            for (int kt = 0; kt < 4; ++kt)
                #pragma unroll
                for (int r = 0; r < 4; ++r) {
                    sA[kt][r] = __expf(sA[kt][r] - mA); psA += sA[kt][r];
                    sB[kt][r] = __expf(sB[kt][r] - mB); psB += sB[kt][r];
                }
            psA += __shfl_xor(psA, 16);
            psA += __shfl_xor(psA, 32);
            psB += __shfl_xor(psB, 16);
            psB += __shfl_xor(psB, 32);
            lsumA += psA;
            lsumB += psB;

            // ---- P^T -> LDS [q][key], cvt_pk packed (same-wave roundtrip) ----
            #pragma unroll
            for (int kt = 0; kt < 4; ++kt) {
                uint2 pkA, pkB;
                pkA.x = cvtpk(sA[kt][0], sA[kt][1]);
                pkA.y = cvtpk(sA[kt][2], sA[kt][3]);
                pkB.x = cvtpk(sB[kt][0], sB[kt][1]);
                pkB.y = cvtpk(sB[kt][2], sB[kt][3]);
                *reinterpret_cast<uint2*>(&sm.st.Pl[w][llo][kt * 16 + lhi * 4]) = pkA;
                *reinterpret_cast<uint2*>(&sm.st.Pl[w][16 + llo][kt * 16 + lhi * 4]) = pkB;
            }
            bf16x8 pfA0 = *reinterpret_cast<const bf16x8*>(&sm.st.Pl[w][llo][lhi * 8]);
            bf16x8 pfA1 = *reinterpret_cast<const bf16x8*>(&sm.st.Pl[w][llo][32 + lhi * 8]);
            bf16x8 pfB0 = *reinterpret_cast<const bf16x8*>(&sm.st.Pl[w][16 + llo][lhi * 8]);
            bf16x8 pfB1 = *reinterpret_cast<const bf16x8*>(&sm.st.Pl[w][16 + llo][32 + lhi * 8]);

            // ---- O^T += V^T P for both strips (V frags read once) ----
            __builtin_amdgcn_s_setprio(1);
            #pragma unroll
            for (int dt = 0; dt < 4; ++dt) {
                const int rbo = tb + ((dt * 16 + llo) * 64) * 2;
                bf16x8 va = *reinterpret_cast<const bf16x8*>(swzp(sm.st.V, rbo + lhi * 16));
                bf16x8 vb = *reinterpret_cast<const bf16x8*>(swzp(sm.st.V, rbo + 64 + lhi * 16));
                accA[dt] = __builtin_amdgcn_mfma_f32_16x16x32_bf16(va, pfA0, accA[dt], 0, 0, 0);
                accA[dt] = __builtin_amdgcn_mfma_f32_16x16x32_bf16(vb, pfA1, accA[dt], 0, 0, 0);
                accB[dt] = __builtin_amdgcn_mfma_f32_16x16x32_bf16(va, pfB0, accB[dt], 0, 0, 0);
                accB[dt] = __builtin_amdgcn_mfma_f32_16x16x32_bf16(vb, pfB1, accB[dt], 0, 0, 0);
            }
            __builtin_amdgcn_s_setprio(0);
        }
    }

    // ---- 2-way in-block flash combine (g=0 merges g=1) ----
    __syncthreads();
    const int rowA = wq2 * 32 + llo;
    const int rowB = rowA + 16;
    if (g == 1) {
        #pragma unroll
        for (int dt = 0; dt < 4; ++dt) {
            float4 oA = {accA[dt][0], accA[dt][1], accA[dt][2], accA[dt][3]};
            float4 oB = {accB[dt][0], accB[dt][1], accB[dt][2], accB[dt][3]};
            *reinterpret_cast<float4*>(&sm.cb.O[rowA][dt * 16 + lhi * 4]) = oA;
            *reinterpret_cast<float4*>(&sm.cb.O[rowB][dt * 16 + lhi * 4]) = oB;
        }
        if (lhi == 0) {
            sm.cb.ml[rowA][0] = mA; sm.cb.ml[rowA][1] = lsumA;
            sm.cb.ml[rowB][0] = mB; sm.cb.ml[rowB][1] = lsumB;
        }
    }
    __syncthreads();
    if (g == 0) {
        #pragma unroll
        for (int st = 0; st < 2; ++st) {
            const int row = (st == 0) ? rowA : rowB;
            const float mreg = (st == 0) ? mA : mB;
            const float lreg = (st == 0) ? lsumA : lsumB;
            const f32x4* accp = (st == 0) ? accA : accB;
            const float mg = sm.cb.ml[row][0];
            const float lg = sm.cb.ml[row][1];
            const float M  = fmaxf(mreg, mg);
            const float a0 = __expf(mreg - M);
            const float a1 = __expf(mg - M);
            const float L  = lreg * a0 + lg * a1;
            if (nch == 1) {
                const float invL = 1.f / L;
                float* orow = out + ((size_t)b * SS + q0 + row) * HH;
                #pragma unroll
                for (int dt = 0; dt < 4; ++dt) {
                    const float4 o2 = *reinterpret_cast<const float4*>(&sm.cb.O[row][dt * 16 + lhi * 4]);
                    float4 o;
                    o.x = (accp[dt][0] * a0 + o2.x * a1) * invL;
                    o.y = (accp[dt][1] * a0 + o2.y * a1) * invL;
                    o.z = (accp[dt][2] * a0 + o2.z * a1) * invL;
                    o.w = (accp[dt][3] * a0 + o2.w * a1) * invL;
                    *reinterpret_cast<float4*>(&orow[dt * 16 + lhi * 4]) = o;
                }
            } else {
                float* PoT  = Po  + (((size_t)(b * 64 + qb) * 4 + c) << 12);
                float* PmlT = Pml + (((size_t)(b * 64 + qb) * 4 + c) << 7);
                #pragma unroll
                for (int dt = 0; dt < 4; ++dt) {
                    const float4 o2 = *reinterpret_cast<const float4*>(&sm.cb.O[row][dt * 16 + lhi * 4]);
                    float4 o;
                    o.x = accp[dt][0] * a0 + o2.x * a1;
                    o.y = accp[dt][1] * a0 + o2.y * a1;
                    o.z = accp[dt][2] * a0 + o2.z * a1;
                    o.w = accp[dt][3] * a0 + o2.w * a1;
                    *reinterpret_cast<float4*>(&PoT[row * 64 + dt * 16 + lhi * 4]) = o;
                }
                if (lhi == 0) { PmlT[row] = M; PmlT[64 + row] = L; }
            }
        }
    }
}

// ---------------- Partial combine: q-tiles 16..63 (2..4 chunks each) ----------------
__global__ __launch_bounds__(256) void combine_kernel(
    const float* __restrict__ Po, const float* __restrict__ Pml, float* __restrict__ out)
{
    const int qt = 16 + blockIdx.x;
    const int b  = blockIdx.y;
    const int nch = qt / 16 + 1;
    const int t = threadIdx.x;
    const int row = t >> 2;
    const int col0 = (t & 3) * 16;
    const size_t baseIdx = (size_t)(b * 64 + qt) * 4;

    float mv[4], lv[4], a[4];
    float M = -INFINITY;
    for (int cc = 0; cc < nch; ++cc) {
        const float* PmlT = Pml + ((baseIdx + cc) << 7);
        mv[cc] = PmlT[row];
        lv[cc] = PmlT[64 + row];
        M = fmaxf(M, mv[cc]);
    }
    float L = 0.f;
    for (int cc = 0; cc < nch; ++cc) { a[cc] = __expf(mv[cc] - M); L += a[cc] * lv[cc]; }
    const float invL = 1.f / L;

    #pragma unroll
    for (int j = 0; j < 4; ++j) {
        float4 s = {0.f, 0.f, 0.f, 0.f};
        for (int cc = 0; cc < nch; ++cc) {
            const float4 v = *reinterpret_cast<const float4*>(
                &Po[((baseIdx + cc) << 12) + row * 64 + col0 + j * 4]);
            s.x += a[cc] * v.x; s.y += a[cc] * v.y;
            s.z += a[cc] * v.z; s.w += a[cc] * v.w;
        }
        s.x *= invL; s.y *= invL; s.z *= invL; s.w *= invL;
        *reinterpret_cast<float4*>(&out[((size_t)b * SS + qt * 64 + row) * HH + col0 + j * 4]) = s;
    }
}

extern "C" void kernel_launch(void* const* d_in, const int* in_sizes, int n_in,
                              void* d_out, int out_size, void* d_ws, size_t ws_size,
                              hipStream_t stream)
{
    const float* X  = (const float*)d_in[0];
    const float* Wq = (const float*)d_in[1];
    const float* bq = (const float*)d_in[2];
    const float* Wk = (const float*)d_in[3];
    const float* bk = (const float*)d_in[4];
    const float* Wv = (const float*)d_in[5];
    const float* bv = (const float*)d_in[6];

    unsigned short* Qb = (unsigned short*)d_ws;          // 2 MB
    unsigned short* Kb = Qb + (size_t)MM * HH;           // 2 MB
    unsigned short* Vt = Kb + (size_t)MM * HH;           // 2 MB (transposed [B][H][S])
    unsigned short* Wt = Vt + (size_t)MM * HH;           // 288 KB
    float* Po  = (float*)(Wt + (size_t)192 * DD);        // 16 MB
    float* Pml = Po + ((size_t)BB * 64 * 4 << 12);       // 512 KB

    dim3 gw(DD / 64, 3);
    wt_kernel<<<gw, 256, 0, stream>>>(Wq, Wk, Wv, Wt);

    qkv_proj_kernel<<<MM / 32, 512, 0, stream>>>(X, Wt, bq, bk, bv, Qb, Kb, Vt);

    attn_partial_kernel<<<160 * BB, 256, 0, stream>>>(Qb, Kb, Vt, (float*)d_out, Po, Pml);
    dim3 gc(48, BB);
    combine_kernel<<<gc, 256, 0, stream>>>(Po, Pml, (float*)d_out);
}

// Round 17
// 59.432 us; speedup vs baseline: 1.1025x; 1.1025x over previous
//
#include <hip/hip_runtime.h>
#include <math.h>

#define BB 4
#define SS 4096
#define DD 768
#define HH 64
#define MM (BB * SS)

typedef __attribute__((ext_vector_type(8))) short bf16x8;
typedef __attribute__((ext_vector_type(4))) float f32x4;

__device__ inline unsigned short f2bf(float f) {
    union { float f; unsigned u; } x; x.f = f;
    unsigned r = x.u + 0x7fffu + ((x.u >> 16) & 1u);
    return (unsigned short)(r >> 16);
}

// native 2^x (v_exp_f32)
__device__ inline float exp2a(float x) { return exp2f(x); }

// packed f32x2 -> bf16x2 (lo=a, hi=b); no builtin on gfx950, use inline asm (guide T12)
__device__ inline unsigned cvtpk(float a, float b) {
    unsigned r;
    asm("v_cvt_pk_bf16_f32 %0, %1, %2" : "=v"(r) : "v"(a), "v"(b));
    return r;
}

// XOR-swizzle for [rows][64 bf16] (128B-row) LDS tiles: 16B slot ^= row&7.
// Apply on BOTH write and read (same involution both sides).
__device__ inline unsigned short* swzp(unsigned short* base, int byteoff) {
    byteoff ^= ((byteoff >> 7) & 7) << 4;
    return (unsigned short*)((char*)base + byteoff);
}

// ---------------- One-time weight transpose: Wq|Wk|Wv [768,64] fp32 -> Wt [192][768] bf16 ----------------
__global__ __launch_bounds__(256) void wt_kernel(
    const float* __restrict__ Wq, const float* __restrict__ Wk, const float* __restrict__ Wv,
    unsigned short* __restrict__ Wt)
{
    const int kt = blockIdx.x;
    const int sel = blockIdx.y;
    const int k0 = kt * 64;
    const float* W = (sel == 0) ? Wq : (sel == 1) ? Wk : Wv;
    __shared__ float Ws[64][68];
    const int t = threadIdx.x;
    #pragma unroll
    for (int j = 0; j < 4; ++j) {
        const int fl = t + j * 256;
        const int row = fl >> 4, c4 = (fl & 15) * 4;
        float4 v = *reinterpret_cast<const float4*>(&W[(size_t)(k0 + row) * HH + c4]);
        Ws[row][c4 + 0] = v.x; Ws[row][c4 + 1] = v.y;
        Ws[row][c4 + 2] = v.z; Ws[row][c4 + 3] = v.w;
    }
    __syncthreads();
    const int n = t >> 2;
    const int c8 = (t & 3) * 16;
    unsigned short tmp[16];
    #pragma unroll
    for (int j = 0; j < 16; ++j) tmp[j] = f2bf(Ws[c8 + j][n]);
    unsigned short* dst = &Wt[((size_t)sel * 64 + n) * DD + k0 + c8];
    *reinterpret_cast<bf16x8*>(dst)     = *reinterpret_cast<bf16x8*>(&tmp[0]);
    *reinterpret_cast<bf16x8*>(dst + 8) = *reinterpret_cast<bf16x8*>(&tmp[8]);
}

// ---------------- QKV projection via MFMA: M=32, N=192, BK=64, reg ping-pong, swizzled LDS ----------------
// Q is pre-scaled by 0.125*log2e so attention works in exp2 domain.
#define VTP 40
#define QSCALE 0.18033688011112042f   // 0.125 * log2(e)
__global__ __launch_bounds__(512) void qkv_proj_kernel(
    const float* __restrict__ X, const unsigned short* __restrict__ Wt,
    const float* __restrict__ bq, const float* __restrict__ bk, const float* __restrict__ bv,
    unsigned short* __restrict__ Qb, unsigned short* __restrict__ Kb,
    unsigned short* __restrict__ Vt)
{
    __shared__ unsigned short Alds[32 * 64];
    __shared__ unsigned short Blds[192 * 64];

    const int tid = threadIdx.x;
    const int rowBase = blockIdx.x * 32;
    const int w = tid >> 6;
    const int ms = w & 1;
    const int nq = w >> 1;
    const int lane = tid & 63;
    const int lhi = lane >> 4, llo = lane & 15;

    f32x4 acc[3] = {{0,0,0,0},{0,0,0,0},{0,0,0,0}};

    const int arow = tid >> 4;
    const int ac   = (tid & 15) * 4;

    float4 xA, xB;
    bf16x8 bA[3], bB[3];

    auto loadP = [&](int kb, float4& x0, bf16x8 (&bb)[3]) {
        const int kBase = kb * 64;
        x0 = *reinterpret_cast<const float4*>(&X[(size_t)(rowBase + arow) * DD + kBase + ac]);
        #pragma unroll
        for (int i = 0; i < 3; ++i) {
            const int u = tid + i * 512;
            const int n = u >> 3, c8 = (u & 7) * 8;
            bb[i] = *reinterpret_cast<const bf16x8*>(&Wt[(size_t)n * DD + kBase + c8]);
        }
    };
    auto writeP = [&](const float4& x0, bf16x8 (&bb)[3]) {
        uint2 pk;
        pk.x = cvtpk(x0.x, x0.y);
        pk.y = cvtpk(x0.z, x0.w);
        *reinterpret_cast<uint2*>(swzp(Alds, (arow * 64 + ac) * 2)) = pk;
        #pragma unroll
        for (int i = 0; i < 3; ++i) {
            const int u = tid + i * 512;
            const int n = u >> 3, c8 = (u & 7) * 8;
            *reinterpret_cast<bf16x8*>(swzp(Blds, (n * 64 + c8) * 2)) = bb[i];
        }
    };

    loadP(0, xA, bA);

    for (int kb = 0; kb < DD / 64; ++kb) {
        __syncthreads();
        if ((kb & 1) == 0) {
            writeP(xA, bA);
            if (kb + 1 < DD / 64) loadP(kb + 1, xB, bB);
        } else {
            writeP(xB, bB);
            if (kb + 1 < DD / 64) loadP(kb + 1, xA, bA);
        }
        __syncthreads();

        #pragma unroll
        for (int kk = 0; kk < 2; ++kk) {
            const int aoff = kk * 32 + lhi * 8;
            bf16x8 af = *reinterpret_cast<const bf16x8*>(
                swzp(Alds, ((ms * 16 + llo) * 64 + aoff) * 2));
            #pragma unroll
            for (int nt = 0; nt < 3; ++nt) {
                bf16x8 bf = *reinterpret_cast<const bf16x8*>(
                    swzp(Blds, ((nq * 48 + nt * 16 + llo) * 64 + aoff) * 2));
                acc[nt] = __builtin_amdgcn_mfma_f32_16x16x32_bf16(af, bf, acc[nt], 0, 0, 0);
            }
        }
    }

    // ---- epilogue ----
    __syncthreads();
    unsigned short* VtLds = Blds;   // [64 nn][VTP] bf16

    #pragma unroll
    for (int nt = 0; nt < 3; ++nt) {
        const int n = nq * 48 + nt * 16 + llo;
        const int sel = n >> 6;
        const int nn = n & 63;
        const float bias = (sel == 0) ? bq[nn] : (sel == 1) ? bk[nn] : bv[nn];
        if (sel == 0) {
            #pragma unroll
            for (int r = 0; r < 4; ++r) {
                const int row = rowBase + ms * 16 + lhi * 4 + r;
                Qb[(size_t)row * HH + nn] = f2bf((acc[nt][r] + bias) * QSCALE);
            }
        } else if (sel == 1) {
            #pragma unroll
            for (int r = 0; r < 4; ++r) {
                const int row = rowBase + ms * 16 + lhi * 4 + r;
                Kb[(size_t)row * HH + nn] = f2bf(acc[nt][r] + bias);
            }
        } else {
            uint2 pk;
            pk.x = cvtpk(acc[nt][0] + bias, acc[nt][1] + bias);
            pk.y = cvtpk(acc[nt][2] + bias, acc[nt][3] + bias);
            *reinterpret_cast<uint2*>(&VtLds[nn * VTP + ms * 16 + lhi * 4]) = pk;
        }
    }
    __syncthreads();
    if (tid < 256) {
        const int nn = tid >> 2;
        const int s8 = (tid & 3) * 8;
        const int bb = rowBase >> 12;
        const int sbase = rowBase & (SS - 1);
        bf16x8 v = *reinterpret_cast<const bf16x8*>(&VtLds[nn * VTP + s8]);
        *reinterpret_cast<bf16x8*>(&Vt[((size_t)bb * HH + nn) * SS + sbase + s8]) = v;
    }
}

// ---------------- Split-K MFMA flash attention (R14 structure, exp2-domain softmax) ----------------
union SMemA {
    struct {
        unsigned short K[2 * 4096];          // 2 tiles [64][64], swizzled  (16 KB)
        unsigned short V[2 * 4096];          // 2 tiles [64][64], swizzled  (16 KB)
        unsigned short Pl[8][16][72];        // per-wave P, unswizzled      (18 KB)
    } st;
    struct { float O[4][16][68]; float ml[4][16][2]; } cb;   // 17920 B
};

__global__ __launch_bounds__(512, 4) void attn_partial_kernel(
    const unsigned short* __restrict__ Qg, const unsigned short* __restrict__ Kg,
    const unsigned short* __restrict__ Vtg, float* __restrict__ out,
    float* __restrict__ Po, float* __restrict__ Pml)
{
    __shared__ SMemA sm;

    // ---- LPT (longest-first) decode: idx -> (b, qb, c) ----
    const int idx = blockIdx.x;
    const int l = idx >> 2;
    const int b = idx & 3;
    int qb, c;
    if (l < 49)       { qb = 15 + l;        c = 0; }
    else if (l < 82)  { qb = 31 + (l - 49); c = 1; }
    else if (l < 99)  { qb = 47 + (l - 82); c = 2; }
    else if (l == 99) { qb = 63;            c = 3; }
    else {
        const int j = l - 100;
        const int s = 15 - (j >> 2);
        const int k = j & 3;
        qb = (s - 1) + 16 * k;
        c = k;
    }

    const int tid = threadIdx.x;
    const int q0 = qb * 64;
    const int w   = tid >> 6;        // 0..7
    const int g   = w >> 2;          // tile parity
    const int wq  = w & 3;           // q strip
    const int lane = tid & 63;
    const int lhi = lane >> 4, llo = lane & 15;
    const int qw0 = q0 + wq * 16;
    const int qme = qw0 + llo;       // this lane's q row

    const int ntiles = qb + 1;
    const int base0 = c * 16;
    const int endT = min(base0 + 16, ntiles);
    const int nsteps = (endT - base0 + 1) >> 1;
    const int nch = qb / 16 + 1;

    const unsigned short* Kbase = Kg  + (size_t)b * SS * HH;
    const unsigned short* Vbase = Vtg + (size_t)b * HH * SS;

    // Q fragment (B operand): lane holds Q[qme][k] (pre-scaled by 0.125*log2e)
    bf16x8 qf0, qf1;
    {
        const unsigned short* qrow = Qg + ((size_t)b * SS + qme) * HH + lhi * 8;
        qf0 = *reinterpret_cast<const bf16x8*>(qrow);
        qf1 = *reinterpret_cast<const bf16x8*>(qrow + 32);
    }

    float m = -INFINITY, lsum = 0.f;   // m in log2 domain
    f32x4 acc[4] = {{0,0,0,0},{0,0,0,0},{0,0,0,0},{0,0,0,0}};

    // staging coords: thread stages one bf16x8 per tile (2 K + 2 V)
    const int srow = tid >> 3;        // 0..63
    const int sc8  = (tid & 7) * 8;   // 0..56

    bf16x8 rA[4] = {{0,0,0,0,0,0,0,0},{0,0,0,0,0,0,0,0},{0,0,0,0,0,0,0,0},{0,0,0,0,0,0,0,0}};
    bf16x8 rB[4] = {{0,0,0,0,0,0,0,0},{0,0,0,0,0,0,0,0},{0,0,0,0,0,0,0,0},{0,0,0,0,0,0,0,0}};

    auto load_step = [&](int base, bf16x8 (&rg)[4]) {
        #pragma unroll
        for (int i = 0; i < 4; ++i) {
            const int t = base + (i & 1);
            if (t < endT) {
                rg[i] = (i < 2)
                    ? *reinterpret_cast<const bf16x8*>(&Kbase[(size_t)(t * 64 + srow) * HH + sc8])
                    : *reinterpret_cast<const bf16x8*>(&Vbase[(size_t)srow * SS + t * 64 + sc8]);
            }
        }
    };
    auto write_step = [&](bf16x8 (&rg)[4]) {
        const int ro = (srow * 64 + sc8) * 2;           // byte offset within a tile
        *reinterpret_cast<bf16x8*>(swzp(sm.st.K, ro))         = rg[0];
        *reinterpret_cast<bf16x8*>(swzp(sm.st.K, 8192 + ro))  = rg[1];
        *reinterpret_cast<bf16x8*>(swzp(sm.st.V, ro))         = rg[2];
        *reinterpret_cast<bf16x8*>(swzp(sm.st.V, 8192 + ro))  = rg[3];
    };

    load_step(base0, rA);

    for (int stp = 0; stp < nsteps; ++stp) {
        const int base = base0 + stp * 2;
        __syncthreads();   // previous step's LDS readers done
        if ((stp & 1) == 0) {
            write_step(rA);
            if (stp + 1 < nsteps) load_step(base + 2, rB);
        } else {
            write_step(rB);
            if (stp + 1 < nsteps) load_step(base + 2, rA);
        }
        __syncthreads();   // LDS ready

        const int lt = base + g;
        if (lt < endT) {
            const int k0 = lt * 64;
            const int tb = g * 8192;   // tile byte base

            // ---- S^T = K Q^T (log2-domain scores) ----
            f32x4 s[4] = {{0,0,0,0},{0,0,0,0},{0,0,0,0},{0,0,0,0}};
            __builtin_amdgcn_s_setprio(1);
            #pragma unroll
            for (int kt = 0; kt < 4; ++kt) {
                const int rbo = tb + ((kt * 16 + llo) * 64) * 2;
                bf16x8 ka = *reinterpret_cast<const bf16x8*>(swzp(sm.st.K, rbo + lhi * 16));
                bf16x8 kb = *reinterpret_cast<const bf16x8*>(swzp(sm.st.K, rbo + 64 + lhi * 16));
                s[kt] = __builtin_amdgcn_mfma_f32_16x16x32_bf16(ka, qf0, s[kt], 0, 0, 0);
                s[kt] = __builtin_amdgcn_mfma_f32_16x16x32_bf16(kb, qf1, s[kt], 0, 0, 0);
            }
            __builtin_amdgcn_s_setprio(0);

            // ---- causal mask (diagonal tiles only) ----
            if (k0 + 63 > qw0) {
                #pragma unroll
                for (int kt = 0; kt < 4; ++kt) {
                    #pragma unroll
                    for (int r = 0; r < 4; ++r) {
                        const int key = k0 + kt * 16 + lhi * 4 + r;
                        if (key > qme) s[kt][r] = -INFINITY;
                    }
                }
            }

            // ---- per-lane online softmax (16 in-lane + 2 shfl), defer-max, exp2 ----
            float mx = s[0][0];
            #pragma unroll
            for (int kt = 0; kt < 4; ++kt)
                #pragma unroll
                for (int r = 0; r < 4; ++r) mx = fmaxf(mx, s[kt][r]);
            mx = fmaxf(mx, __shfl_xor(mx, 16));
            mx = fmaxf(mx, __shfl_xor(mx, 32));
            if (!__all(mx - m <= 11.5416f)) {    // = 8 * log2(e)
                const float mn = fmaxf(m, mx);
                const float corr = exp2a(m - mn);
                lsum *= corr;
                #pragma unroll
                for (int dt = 0; dt < 4; ++dt)
                    #pragma unroll
                    for (int r = 0; r < 4; ++r) acc[dt][r] *= corr;
                m = mn;
            }
            float ps = 0.f;
            #pragma unroll
            for (int kt = 0; kt < 4; ++kt)
                #pragma unroll
                for (int r = 0; r < 4; ++r) { s[kt][r] = exp2a(s[kt][r] - m); ps += s[kt][r]; }
            ps += __shfl_xor(ps, 16);
            ps += __shfl_xor(ps, 32);
            lsum += ps;

            // ---- P^T -> LDS [q=llo][key], cvt_pk packed b64 (same-wave roundtrip) ----
            #pragma unroll
            for (int kt = 0; kt < 4; ++kt) {
                uint2 pk;
                pk.x = cvtpk(s[kt][0], s[kt][1]);
                pk.y = cvtpk(s[kt][2], s[kt][3]);
                *reinterpret_cast<uint2*>(&sm.st.Pl[w][llo][kt * 16 + lhi * 4]) = pk;
            }
            bf16x8 pf0 = *reinterpret_cast<const bf16x8*>(&sm.st.Pl[w][llo][lhi * 8]);
            bf16x8 pf1 = *reinterpret_cast<const bf16x8*>(&sm.st.Pl[w][llo][32 + lhi * 8]);

            // ---- O^T += V^T P ----
            __builtin_amdgcn_s_setprio(1);
            #pragma unroll
            for (int dt = 0; dt < 4; ++dt) {
                const int rbo = tb + ((dt * 16 + llo) * 64) * 2;
                bf16x8 va = *reinterpret_cast<const bf16x8*>(swzp(sm.st.V, rbo + lhi * 16));
                bf16x8 vb = *reinterpret_cast<const bf16x8*>(swzp(sm.st.V, rbo + 64 + lhi * 16));
                acc[dt] = __builtin_amdgcn_mfma_f32_16x16x32_bf16(va, pf0, acc[dt], 0, 0, 0);
                acc[dt] = __builtin_amdgcn_mfma_f32_16x16x32_bf16(vb, pf1, acc[dt], 0, 0, 0);
            }
            __builtin_amdgcn_s_setprio(0);
        }
    }

    // ---- 2-way in-block flash combine (g=0 merges g=1), exp2 domain ----
    __syncthreads();
    if (g == 1) {
        #pragma unroll
        for (int dt = 0; dt < 4; ++dt) {
            float4 o4 = {acc[dt][0], acc[dt][1], acc[dt][2], acc[dt][3]};
            *reinterpret_cast<float4*>(&sm.cb.O[wq][llo][dt * 16 + lhi * 4]) = o4;
        }
        if (lhi == 0) { sm.cb.ml[wq][llo][0] = m; sm.cb.ml[wq][llo][1] = lsum; }
    }
    __syncthreads();
    if (g == 0) {
        const float mg = sm.cb.ml[wq][llo][0];
        const float lg = sm.cb.ml[wq][llo][1];
        const float M  = fmaxf(m, mg);
        const float a0 = exp2a(m - M);
        const float a1 = exp2a(mg - M);
        const float L  = lsum * a0 + lg * a1;
        if (nch == 1) {
            const float invL = 1.f / L;
            float* orow = out + ((size_t)b * SS + qme) * HH;
            #pragma unroll
            for (int dt = 0; dt < 4; ++dt) {
                const float4 o2 = *reinterpret_cast<const float4*>(&sm.cb.O[wq][llo][dt * 16 + lhi * 4]);
                float4 o;
                o.x = (acc[dt][0] * a0 + o2.x * a1) * invL;
                o.y = (acc[dt][1] * a0 + o2.y * a1) * invL;
                o.z = (acc[dt][2] * a0 + o2.z * a1) * invL;
                o.w = (acc[dt][3] * a0 + o2.w * a1) * invL;
                *reinterpret_cast<float4*>(&orow[dt * 16 + lhi * 4]) = o;
            }
        } else {
            float* PoT  = Po  + (((size_t)(b * 64 + qb) * 4 + c) << 12);
            float* PmlT = Pml + (((size_t)(b * 64 + qb) * 4 + c) << 7);
            const int row = wq * 16 + llo;
            #pragma unroll
            for (int dt = 0; dt < 4; ++dt) {
                const float4 o2 = *reinterpret_cast<const float4*>(&sm.cb.O[wq][llo][dt * 16 + lhi * 4]);
                float4 o;
                o.x = acc[dt][0] * a0 + o2.x * a1;
                o.y = acc[dt][1] * a0 + o2.y * a1;
                o.z = acc[dt][2] * a0 + o2.z * a1;
                o.w = acc[dt][3] * a0 + o2.w * a1;
                *reinterpret_cast<float4*>(&PoT[row * 64 + dt * 16 + lhi * 4]) = o;
            }
            if (lhi == 0) { PmlT[row] = M; PmlT[64 + row] = L; }
        }
    }
}

// ---------------- Partial combine: q-tiles 16..63 (2..4 chunks each), exp2 domain ----------------
__global__ __launch_bounds__(256) void combine_kernel(
    const float* __restrict__ Po, const float* __restrict__ Pml, float* __restrict__ out)
{
    const int qt = 16 + blockIdx.x;
    const int b  = blockIdx.y;
    const int nch = qt / 16 + 1;
    const int t = threadIdx.x;
    const int row = t >> 2;
    const int col0 = (t & 3) * 16;
    const size_t baseIdx = (size_t)(b * 64 + qt) * 4;

    float mv[4], lv[4], a[4];
    float M = -INFINITY;
    for (int cc = 0; cc < nch; ++cc) {
        const float* PmlT = Pml + ((baseIdx + cc) << 7);
        mv[cc] = PmlT[row];
        lv[cc] = PmlT[64 + row];
        M = fmaxf(M, mv[cc]);
    }
    float L = 0.f;
    for (int cc = 0; cc < nch; ++cc) { a[cc] = exp2f(mv[cc] - M); L += a[cc] * lv[cc]; }
    const float invL = 1.f / L;

    #pragma unroll
    for (int j = 0; j < 4; ++j) {
        float4 s = {0.f, 0.f, 0.f, 0.f};
        for (int cc = 0; cc < nch; ++cc) {
            const float4 v = *reinterpret_cast<const float4*>(
                &Po[((baseIdx + cc) << 12) + row * 64 + col0 + j * 4]);
            s.x += a[cc] * v.x; s.y += a[cc] * v.y;
            s.z += a[cc] * v.z; s.w += a[cc] * v.w;
        }
        s.x *= invL; s.y *= invL; s.z *= invL; s.w *= invL;
        *reinterpret_cast<float4*>(&out[((size_t)b * SS + qt * 64 + row) * HH + col0 + j * 4]) = s;
    }
}

extern "C" void kernel_launch(void* const* d_in, const int* in_sizes, int n_in,
                              void* d_out, int out_size, void* d_ws, size_t ws_size,
                              hipStream_t stream)
{
    const float* X  = (const float*)d_in[0];
    const float* Wq = (const float*)d_in[1];
    const float* bq = (const float*)d_in[2];
    const float* Wk = (const float*)d_in[3];
    const float* bk = (const float*)d_in[4];
    const float* Wv = (const float*)d_in[5];
    const float* bv = (const float*)d_in[6];

    unsigned short* Qb = (unsigned short*)d_ws;          // 2 MB
    unsigned short* Kb = Qb + (size_t)MM * HH;           // 2 MB
    unsigned short* Vt = Kb + (size_t)MM * HH;           // 2 MB (transposed [B][H][S])
    unsigned short* Wt = Vt + (size_t)MM * HH;           // 288 KB
    float* Po  = (float*)(Wt + (size_t)192 * DD);        // 16 MB
    float* Pml = Po + ((size_t)BB * 64 * 4 << 12);       // 512 KB

    dim3 gw(DD / 64, 3);
    wt_kernel<<<gw, 256, 0, stream>>>(Wq, Wk, Wv, Wt);

    qkv_proj_kernel<<<MM / 32, 512, 0, stream>>>(X, Wt, bq, bk, bv, Qb, Kb, Vt);

    attn_partial_kernel<<<160 * BB, 512, 0, stream>>>(Qb, Kb, Vt, (float*)d_out, Po, Pml);
    dim3 gc(48, BB);
    combine_kernel<<<gc, 256, 0, stream>>>(Po, Pml, (float*)d_out);
}

// Round 18
// 56.289 us; speedup vs baseline: 1.1640x; 1.0558x over previous
//
#include <hip/hip_runtime.h>
#include <math.h>

#define BB 4
#define SS 4096
#define DD 768
#define HH 64
#define MM (BB * SS)

typedef __attribute__((ext_vector_type(8))) short bf16x8;
typedef __attribute__((ext_vector_type(4))) float f32x4;

__device__ inline unsigned short f2bf(float f) {
    union { float f; unsigned u; } x; x.f = f;
    unsigned r = x.u + 0x7fffu + ((x.u >> 16) & 1u);
    return (unsigned short)(r >> 16);
}

// packed f32x2 -> bf16x2 (lo=a, hi=b); no builtin on gfx950, use inline asm (guide T12)
__device__ inline unsigned cvtpk(float a, float b) {
    unsigned r;
    asm("v_cvt_pk_bf16_f32 %0, %1, %2" : "=v"(r) : "v"(a), "v"(b));
    return r;
}

// XOR-swizzle for [rows][64 bf16] (128B-row) LDS tiles: 16B slot ^= row&7.
// Apply on BOTH write and read (same involution both sides).
__device__ inline unsigned short* swzp(unsigned short* base, int byteoff) {
    byteoff ^= ((byteoff >> 7) & 7) << 4;
    return (unsigned short*)((char*)base + byteoff);
}

// ---------------- One-time weight transpose: Wq|Wk|Wv [768,64] fp32 -> Wt [192][768] bf16 ----------------
__global__ __launch_bounds__(256) void wt_kernel(
    const float* __restrict__ Wq, const float* __restrict__ Wk, const float* __restrict__ Wv,
    unsigned short* __restrict__ Wt)
{
    const int kt = blockIdx.x;
    const int sel = blockIdx.y;
    const int k0 = kt * 64;
    const float* W = (sel == 0) ? Wq : (sel == 1) ? Wk : Wv;
    __shared__ float Ws[64][68];
    const int t = threadIdx.x;
    #pragma unroll
    for (int j = 0; j < 4; ++j) {
        const int fl = t + j * 256;
        const int row = fl >> 4, c4 = (fl & 15) * 4;
        float4 v = *reinterpret_cast<const float4*>(&W[(size_t)(k0 + row) * HH + c4]);
        Ws[row][c4 + 0] = v.x; Ws[row][c4 + 1] = v.y;
        Ws[row][c4 + 2] = v.z; Ws[row][c4 + 3] = v.w;
    }
    __syncthreads();
    const int n = t >> 2;
    const int c8 = (t & 3) * 16;
    unsigned short tmp[16];
    #pragma unroll
    for (int j = 0; j < 16; ++j) tmp[j] = f2bf(Ws[c8 + j][n]);
    unsigned short* dst = &Wt[((size_t)sel * 64 + n) * DD + k0 + c8];
    *reinterpret_cast<bf16x8*>(dst)     = *reinterpret_cast<bf16x8*>(&tmp[0]);
    *reinterpret_cast<bf16x8*>(dst + 8) = *reinterpret_cast<bf16x8*>(&tmp[8]);
}

// ---------------- QKV projection via MFMA: M=32, N=192, BK=64, reg ping-pong, swizzled LDS ----------------
// V output routed through LDS transpose buffer for coalesced 16B stores.
#define VTP 40   // VtLds pitch (bf16): 80B rows -> 16B-aligned, <=2-way banks
__global__ __launch_bounds__(512) void qkv_proj_kernel(
    const float* __restrict__ X, const unsigned short* __restrict__ Wt,
    const float* __restrict__ bq, const float* __restrict__ bk, const float* __restrict__ bv,
    unsigned short* __restrict__ Qb, unsigned short* __restrict__ Kb,
    unsigned short* __restrict__ Vt)
{
    __shared__ unsigned short Alds[32 * 64];
    __shared__ unsigned short Blds[192 * 64];

    const int tid = threadIdx.x;
    const int rowBase = blockIdx.x * 32;
    const int w = tid >> 6;
    const int ms = w & 1;
    const int nq = w >> 1;
    const int lane = tid & 63;
    const int lhi = lane >> 4, llo = lane & 15;

    f32x4 acc[3] = {{0,0,0,0},{0,0,0,0},{0,0,0,0}};

    const int arow = tid >> 4;
    const int ac   = (tid & 15) * 4;

    float4 xA, xB;
    bf16x8 bA[3], bB[3];

    auto loadP = [&](int kb, float4& x0, bf16x8 (&bb)[3]) {
        const int kBase = kb * 64;
        x0 = *reinterpret_cast<const float4*>(&X[(size_t)(rowBase + arow) * DD + kBase + ac]);
        #pragma unroll
        for (int i = 0; i < 3; ++i) {
            const int u = tid + i * 512;
            const int n = u >> 3, c8 = (u & 7) * 8;
            bb[i] = *reinterpret_cast<const bf16x8*>(&Wt[(size_t)n * DD + kBase + c8]);
        }
    };
    auto writeP = [&](const float4& x0, bf16x8 (&bb)[3]) {
        uint2 pk;
        pk.x = cvtpk(x0.x, x0.y);
        pk.y = cvtpk(x0.z, x0.w);
        *reinterpret_cast<uint2*>(swzp(Alds, (arow * 64 + ac) * 2)) = pk;
        #pragma unroll
        for (int i = 0; i < 3; ++i) {
            const int u = tid + i * 512;
            const int n = u >> 3, c8 = (u & 7) * 8;
            *reinterpret_cast<bf16x8*>(swzp(Blds, (n * 64 + c8) * 2)) = bb[i];
        }
    };

    loadP(0, xA, bA);

    for (int kb = 0; kb < DD / 64; ++kb) {
        __syncthreads();
        if ((kb & 1) == 0) {
            writeP(xA, bA);
            if (kb + 1 < DD / 64) loadP(kb + 1, xB, bB);
        } else {
            writeP(xB, bB);
            if (kb + 1 < DD / 64) loadP(kb + 1, xA, bA);
        }
        __syncthreads();

        #pragma unroll
        for (int kk = 0; kk < 2; ++kk) {
            const int aoff = kk * 32 + lhi * 8;
            bf16x8 af = *reinterpret_cast<const bf16x8*>(
                swzp(Alds, ((ms * 16 + llo) * 64 + aoff) * 2));
            #pragma unroll
            for (int nt = 0; nt < 3; ++nt) {
                bf16x8 bf = *reinterpret_cast<const bf16x8*>(
                    swzp(Blds, ((nq * 48 + nt * 16 + llo) * 64 + aoff) * 2));
                acc[nt] = __builtin_amdgcn_mfma_f32_16x16x32_bf16(af, bf, acc[nt], 0, 0, 0);
            }
        }
    }

    // ---- epilogue ----
    __syncthreads();   // all Blds reads done before aliasing as VtLds
    unsigned short* VtLds = Blds;   // [64 nn][VTP] bf16

    #pragma unroll
    for (int nt = 0; nt < 3; ++nt) {
        const int n = nq * 48 + nt * 16 + llo;
        const int sel = n >> 6;
        const int nn = n & 63;
        const float bias = (sel == 0) ? bq[nn] : (sel == 1) ? bk[nn] : bv[nn];
        if (sel == 0) {
            #pragma unroll
            for (int r = 0; r < 4; ++r) {
                const int row = rowBase + ms * 16 + lhi * 4 + r;
                Qb[(size_t)row * HH + nn] = f2bf((acc[nt][r] + bias) * 0.125f);
            }
        } else if (sel == 1) {
            #pragma unroll
            for (int r = 0; r < 4; ++r) {
                const int row = rowBase + ms * 16 + lhi * 4 + r;
                Kb[(size_t)row * HH + nn] = f2bf(acc[nt][r] + bias);
            }
        } else {
            // V: write to LDS transpose buffer [nn][s_local], s_local = ms*16+lhi*4+r
            uint2 pk;
            pk.x = cvtpk(acc[nt][0] + bias, acc[nt][1] + bias);
            pk.y = cvtpk(acc[nt][2] + bias, acc[nt][3] + bias);
            *reinterpret_cast<uint2*>(&VtLds[nn * VTP + ms * 16 + lhi * 4]) = pk;
        }
    }
    __syncthreads();
    // cooperative coalesced store of the [64 nn][32 s] V^T tile
    if (tid < 256) {
        const int nn = tid >> 2;
        const int s8 = (tid & 3) * 8;
        const int bb = rowBase >> 12;
        const int sbase = rowBase & (SS - 1);
        bf16x8 v = *reinterpret_cast<const bf16x8*>(&VtLds[nn * VTP + s8]);
        *reinterpret_cast<bf16x8*>(&Vt[((size_t)bb * HH + nn) * SS + sbase + s8]) = v;
    }
}

// ---------------- Split-K MFMA flash attention: swizzled LDS + defer-max + setprio ----------------
union SMemA {
    struct {
        unsigned short K[2 * 4096];          // 2 tiles [64][64], swizzled  (16 KB)
        unsigned short V[2 * 4096];          // 2 tiles [64][64], swizzled  (16 KB)
        unsigned short Pl[8][16][72];        // per-wave P, unswizzled      (18 KB)
    } st;
    struct { float O[4][16][68]; float ml[4][16][2]; } cb;   // 17920 B
};

__global__ __launch_bounds__(512, 4) void attn_partial_kernel(
    const unsigned short* __restrict__ Qg, const unsigned short* __restrict__ Kg,
    const unsigned short* __restrict__ Vtg, float* __restrict__ out,
    float* __restrict__ Po, float* __restrict__ Pml)
{
    __shared__ SMemA sm;

    // ---- LPT (longest-first) decode: idx -> (b, qb, c) ----
    const int idx = blockIdx.x;
    const int l = idx >> 2;
    const int b = idx & 3;
    int qb, c;
    if (l < 49)       { qb = 15 + l;        c = 0; }
    else if (l < 82)  { qb = 31 + (l - 49); c = 1; }
    else if (l < 99)  { qb = 47 + (l - 82); c = 2; }
    else if (l == 99) { qb = 63;            c = 3; }
    else {
        const int j = l - 100;
        const int s = 15 - (j >> 2);
        const int k = j & 3;
        qb = (s - 1) + 16 * k;
        c = k;
    }

    const int tid = threadIdx.x;
    const int q0 = qb * 64;
    const int w   = tid >> 6;        // 0..7
    const int g   = w >> 2;          // tile parity
    const int wq  = w & 3;           // q strip
    const int lane = tid & 63;
    const int lhi = lane >> 4, llo = lane & 15;
    const int qw0 = q0 + wq * 16;
    const int qme = qw0 + llo;       // this lane's q row

    const int ntiles = qb + 1;
    const int base0 = c * 16;
    const int endT = min(base0 + 16, ntiles);
    const int nsteps = (endT - base0 + 1) >> 1;
    const int nch = qb / 16 + 1;

    const unsigned short* Kbase = Kg  + (size_t)b * SS * HH;
    const unsigned short* Vbase = Vtg + (size_t)b * HH * SS;

    // Q fragment (B operand): lane holds Q[qme][k], k = lhi*8+j (+32)
    bf16x8 qf0, qf1;
    {
        const unsigned short* qrow = Qg + ((size_t)b * SS + qme) * HH + lhi * 8;
        qf0 = *reinterpret_cast<const bf16x8*>(qrow);
        qf1 = *reinterpret_cast<const bf16x8*>(qrow + 32);
    }

    float m = -INFINITY, lsum = 0.f;
    f32x4 acc[4] = {{0,0,0,0},{0,0,0,0},{0,0,0,0},{0,0,0,0}};  // acc[dt][r]: O^T[d=dt*16+lhi*4+r][q=llo]

    // staging coords: thread stages one bf16x8 per tile (2 K + 2 V)
    const int srow = tid >> 3;        // 0..63
    const int sc8  = (tid & 7) * 8;   // 0..56

    bf16x8 rA[4] = {{0,0,0,0,0,0,0,0},{0,0,0,0,0,0,0,0},{0,0,0,0,0,0,0,0},{0,0,0,0,0,0,0,0}};
    bf16x8 rB[4] = {{0,0,0,0,0,0,0,0},{0,0,0,0,0,0,0,0},{0,0,0,0,0,0,0,0},{0,0,0,0,0,0,0,0}};

    auto load_step = [&](int base, bf16x8 (&rg)[4]) {
        #pragma unroll
        for (int i = 0; i < 4; ++i) {
            const int t = base + (i & 1);
            if (t < endT) {
                rg[i] = (i < 2)
                    ? *reinterpret_cast<const bf16x8*>(&Kbase[(size_t)(t * 64 + srow) * HH + sc8])
                    : *reinterpret_cast<const bf16x8*>(&Vbase[(size_t)srow * SS + t * 64 + sc8]);
            }
        }
    };
    auto write_step = [&](bf16x8 (&rg)[4]) {
        const int ro = (srow * 64 + sc8) * 2;           // byte offset within a tile
        *reinterpret_cast<bf16x8*>(swzp(sm.st.K, ro))         = rg[0];
        *reinterpret_cast<bf16x8*>(swzp(sm.st.K, 8192 + ro))  = rg[1];
        *reinterpret_cast<bf16x8*>(swzp(sm.st.V, ro))         = rg[2];
        *reinterpret_cast<bf16x8*>(swzp(sm.st.V, 8192 + ro))  = rg[3];
    };

    load_step(base0, rA);

    for (int stp = 0; stp < nsteps; ++stp) {
        const int base = base0 + stp * 2;
        __syncthreads();   // previous step's LDS readers done
        if ((stp & 1) == 0) {
            write_step(rA);
            if (stp + 1 < nsteps) load_step(base + 2, rB);
        } else {
            write_step(rB);
            if (stp + 1 < nsteps) load_step(base + 2, rA);
        }
        __syncthreads();   // LDS ready

        const int lt = base + g;
        if (lt < endT) {
            const int k0 = lt * 64;
            const int tb = g * 8192;   // tile byte base

            // ---- S^T = K Q^T : s[kt][r] = S[key=k0+kt*16+lhi*4+r][q=qme] ----
            f32x4 s[4] = {{0,0,0,0},{0,0,0,0},{0,0,0,0},{0,0,0,0}};
            __builtin_amdgcn_s_setprio(1);
            #pragma unroll
            for (int kt = 0; kt < 4; ++kt) {
                const int rbo = tb + ((kt * 16 + llo) * 64) * 2;
                bf16x8 ka = *reinterpret_cast<const bf16x8*>(swzp(sm.st.K, rbo + lhi * 16));
                bf16x8 kb = *reinterpret_cast<const bf16x8*>(swzp(sm.st.K, rbo + 64 + lhi * 16));
                s[kt] = __builtin_amdgcn_mfma_f32_16x16x32_bf16(ka, qf0, s[kt], 0, 0, 0);
                s[kt] = __builtin_amdgcn_mfma_f32_16x16x32_bf16(kb, qf1, s[kt], 0, 0, 0);
            }
            __builtin_amdgcn_s_setprio(0);

            // ---- causal mask (diagonal tiles only) ----
            if (k0 + 63 > qw0) {
                #pragma unroll
                for (int kt = 0; kt < 4; ++kt) {
                    #pragma unroll
                    for (int r = 0; r < 4; ++r) {
                        const int key = k0 + kt * 16 + lhi * 4 + r;
                        if (key > qme) s[kt][r] = -INFINITY;
                    }
                }
            }

            // ---- per-lane online softmax (16 in-lane + 2 shfl), defer-max (THR=8) ----
            float mx = s[0][0];
            #pragma unroll
            for (int kt = 0; kt < 4; ++kt)
                #pragma unroll
                for (int r = 0; r < 4; ++r) mx = fmaxf(mx, s[kt][r]);
            mx = fmaxf(mx, __shfl_xor(mx, 16));
            mx = fmaxf(mx, __shfl_xor(mx, 32));
            if (!__all(mx - m <= 8.0f)) {
                const float mn = fmaxf(m, mx);
                const float corr = __expf(m - mn);
                lsum *= corr;
                #pragma unroll
                for (int dt = 0; dt < 4; ++dt)
                    #pragma unroll
                    for (int r = 0; r < 4; ++r) acc[dt][r] *= corr;
                m = mn;
            }
            float ps = 0.f;
            #pragma unroll
            for (int kt = 0; kt < 4; ++kt)
                #pragma unroll
                for (int r = 0; r < 4; ++r) { s[kt][r] = __expf(s[kt][r] - m); ps += s[kt][r]; }
            ps += __shfl_xor(ps, 16);
            ps += __shfl_xor(ps, 32);
            lsum += ps;

            // ---- P^T -> LDS [q=llo][key], cvt_pk packed b64 (same-wave roundtrip) ----
            #pragma unroll
            for (int kt = 0; kt < 4; ++kt) {
                uint2 pk;
                pk.x = cvtpk(s[kt][0], s[kt][1]);
                pk.y = cvtpk(s[kt][2], s[kt][3]);
                *reinterpret_cast<uint2*>(&sm.st.Pl[w][llo][kt * 16 + lhi * 4]) = pk;
            }
            bf16x8 pf0 = *reinterpret_cast<const bf16x8*>(&sm.st.Pl[w][llo][lhi * 8]);
            bf16x8 pf1 = *reinterpret_cast<const bf16x8*>(&sm.st.Pl[w][llo][32 + lhi * 8]);

            // ---- O^T += V^T P ----
            __builtin_amdgcn_s_setprio(1);
            #pragma unroll
            for (int dt = 0; dt < 4; ++dt) {
                const int rbo = tb + ((dt * 16 + llo) * 64) * 2;
                bf16x8 va = *reinterpret_cast<const bf16x8*>(swzp(sm.st.V, rbo + lhi * 16));
                bf16x8 vb = *reinterpret_cast<const bf16x8*>(swzp(sm.st.V, rbo + 64 + lhi * 16));
                acc[dt] = __builtin_amdgcn_mfma_f32_16x16x32_bf16(va, pf0, acc[dt], 0, 0, 0);
                acc[dt] = __builtin_amdgcn_mfma_f32_16x16x32_bf16(vb, pf1, acc[dt], 0, 0, 0);
            }
            __builtin_amdgcn_s_setprio(0);
        }
    }

    // ---- 2-way in-block flash combine (g=0 merges g=1) ----
    __syncthreads();
    if (g == 1) {
        #pragma unroll
        for (int dt = 0; dt < 4; ++dt) {
            float4 o4 = {acc[dt][0], acc[dt][1], acc[dt][2], acc[dt][3]};
            *reinterpret_cast<float4*>(&sm.cb.O[wq][llo][dt * 16 + lhi * 4]) = o4;
        }
        if (lhi == 0) { sm.cb.ml[wq][llo][0] = m; sm.cb.ml[wq][llo][1] = lsum; }
    }
    __syncthreads();
    if (g == 0) {
        const float mg = sm.cb.ml[wq][llo][0];
        const float lg = sm.cb.ml[wq][llo][1];
        const float M  = fmaxf(m, mg);
        const float a0 = __expf(m - M);
        const float a1 = __expf(mg - M);
        const float L  = lsum * a0 + lg * a1;
        if (nch == 1) {
            const float invL = 1.f / L;
            float* orow = out + ((size_t)b * SS + qme) * HH;
            #pragma unroll
            for (int dt = 0; dt < 4; ++dt) {
                const float4 o2 = *reinterpret_cast<const float4*>(&sm.cb.O[wq][llo][dt * 16 + lhi * 4]);
                float4 o;
                o.x = (acc[dt][0] * a0 + o2.x * a1) * invL;
                o.y = (acc[dt][1] * a0 + o2.y * a1) * invL;
                o.z = (acc[dt][2] * a0 + o2.z * a1) * invL;
                o.w = (acc[dt][3] * a0 + o2.w * a1) * invL;
                *reinterpret_cast<float4*>(&orow[dt * 16 + lhi * 4]) = o;
            }
        } else {
            float* PoT  = Po  + (((size_t)(b * 64 + qb) * 4 + c) << 12);
            float* PmlT = Pml + (((size_t)(b * 64 + qb) * 4 + c) << 7);
            const int row = wq * 16 + llo;
            #pragma unroll
            for (int dt = 0; dt < 4; ++dt) {
                const float4 o2 = *reinterpret_cast<const float4*>(&sm.cb.O[wq][llo][dt * 16 + lhi * 4]);
                float4 o;
                o.x = acc[dt][0] * a0 + o2.x * a1;
                o.y = acc[dt][1] * a0 + o2.y * a1;
                o.z = acc[dt][2] * a0 + o2.z * a1;
                o.w = acc[dt][3] * a0 + o2.w * a1;
                *reinterpret_cast<float4*>(&PoT[row * 64 + dt * 16 + lhi * 4]) = o;
            }
            if (lhi == 0) { PmlT[row] = M; PmlT[64 + row] = L; }
        }
    }
}

// ---------------- Partial combine: q-tiles 16..63 (2..4 chunks each) ----------------
__global__ __launch_bounds__(256) void combine_kernel(
    const float* __restrict__ Po, const float* __restrict__ Pml, float* __restrict__ out)
{
    const int qt = 16 + blockIdx.x;
    const int b  = blockIdx.y;
    const int nch = qt / 16 + 1;
    const int t = threadIdx.x;
    const int row = t >> 2;
    const int col0 = (t & 3) * 16;
    const size_t baseIdx = (size_t)(b * 64 + qt) * 4;

    float mv[4], lv[4], a[4];
    float M = -INFINITY;
    for (int cc = 0; cc < nch; ++cc) {
        const float* PmlT = Pml + ((baseIdx + cc) << 7);
        mv[cc] = PmlT[row];
        lv[cc] = PmlT[64 + row];
        M = fmaxf(M, mv[cc]);
    }
    float L = 0.f;
    for (int cc = 0; cc < nch; ++cc) { a[cc] = __expf(mv[cc] - M); L += a[cc] * lv[cc]; }
    const float invL = 1.f / L;

    #pragma unroll
    for (int j = 0; j < 4; ++j) {
        float4 s = {0.f, 0.f, 0.f, 0.f};
        for (int cc = 0; cc < nch; ++cc) {
            const float4 v = *reinterpret_cast<const float4*>(
                &Po[((baseIdx + cc) << 12) + row * 64 + col0 + j * 4]);
            s.x += a[cc] * v.x; s.y += a[cc] * v.y;
            s.z += a[cc] * v.z; s.w += a[cc] * v.w;
        }
        s.x *= invL; s.y *= invL; s.z *= invL; s.w *= invL;
        *reinterpret_cast<float4*>(&out[((size_t)b * SS + qt * 64 + row) * HH + col0 + j * 4]) = s;
    }
}

extern "C" void kernel_launch(void* const* d_in, const int* in_sizes, int n_in,
                              void* d_out, int out_size, void* d_ws, size_t ws_size,
                              hipStream_t stream)
{
    const float* X  = (const float*)d_in[0];
    const float* Wq = (const float*)d_in[1];
    const float* bq = (const float*)d_in[2];
    const float* Wk = (const float*)d_in[3];
    const float* bk = (const float*)d_in[4];
    const float* Wv = (const float*)d_in[5];
    const float* bv = (const float*)d_in[6];

    unsigned short* Qb = (unsigned short*)d_ws;          // 2 MB
    unsigned short* Kb = Qb + (size_t)MM * HH;           // 2 MB
    unsigned short* Vt = Kb + (size_t)MM * HH;           // 2 MB (transposed [B][H][S])
    unsigned short* Wt = Vt + (size_t)MM * HH;           // 288 KB
    float* Po  = (float*)(Wt + (size_t)192 * DD);        // 16 MB
    float* Pml = Po + ((size_t)BB * 64 * 4 << 12);       // 512 KB

    dim3 gw(DD / 64, 3);
    wt_kernel<<<gw, 256, 0, stream>>>(Wq, Wk, Wv, Wt);

    qkv_proj_kernel<<<MM / 32, 512, 0, stream>>>(X, Wt, bq, bk, bv, Qb, Kb, Vt);

    attn_partial_kernel<<<160 * BB, 512, 0, stream>>>(Qb, Kb, Vt, (float*)d_out, Po, Pml);
    dim3 gc(48, BB);
    combine_kernel<<<gc, 256, 0, stream>>>(Po, Pml, (float*)d_out);
}